// Round 4
// baseline (275.293 us; speedup 1.0000x reference)
//
#include <hip/hip_runtime.h>

// Signature-kernel MMD via Goursat PDE — round 6.
// Round-5 postmortem: A/B (r4 scalar vs r5 packed) showed VALUBusy 70->64%
// with dur flat at 100us -> NOT issue-bound; v2f packing added SGPR->VGPR
// marshalling movs (~75 VALU/row measured vs ~47 static). 43us of the
// 143.8us total was sig_diff + inter-kernel launch gaps. The 64 dual-task
// blocks tail a FULL task length, and occupancy reads 48% in every config.
// Round-6: ONE kernel, no workspace.
//  (1) running-dot identity: inc(r,j) = D(r+1)-D(r), D(r)=dot(Xraw[r],dy_j)
//      -> PDE reads RAW X rows (s_load, block-uniform SGPRs) and raw Y
//      (per-lane dy built once per task). sig_diff eliminated.
//  (2) plain fmaf (one SGPR operand each, no v2f movs): ~51 VALU/row.
//  (3) hipMemsetAsync zeroes out; per-block atomicAdd reduce (fused).
//  (4) 2048 blocks (capacity @8/CU), blocks 0..63 run task BT+2048 second.

#define XY_BLOCKS 1024
#define TRI_BLOCKS 544
#define NBT (XY_BLOCKS + 2 * TRI_BLOCKS)        // 2112 block-tasks
#define NBLOCKS6 2048                           // grid = capacity @ 8/CU

template <int C, int RM, int BM, bool BC>
__device__ __forceinline__ float dpp0(float x) {
    return __builtin_bit_cast(float, __builtin_amdgcn_update_dpp(
        0, __builtin_bit_cast(int, x), C, RM, BM, BC));
}

// 64-lane inclusive prefix sum, pure VALU (6 dependent adds).
__device__ __forceinline__ float wave_scan_incl(float v) {
    v += dpp0<0x111, 0xf, 0xf, true>(v);   // row_shr:1
    v += dpp0<0x112, 0xf, 0xf, true>(v);   // row_shr:2
    v += dpp0<0x114, 0xf, 0xf, true>(v);   // row_shr:4
    v += dpp0<0x118, 0xf, 0xf, true>(v);   // row_shr:8
    v += dpp0<0x142, 0xa, 0xf, false>(v);  // row_bcast:15 -> rows 1,3
    v += dpp0<0x143, 0xc, 0xf, false>(v);  // row_bcast:31 -> rows 2,3
    return v;
}

// lane l gets lane l-1's x; lane 0 gets `oldv`.
__device__ __forceinline__ float wave_shr1(float x, float oldv) {
    return __builtin_bit_cast(float, __builtin_amdgcn_update_dpp(
        __builtin_bit_cast(int, oldv), __builtin_bit_cast(int, x),
        0x138, 0xf, 0xf, false));          // wave_shr:1
}

// ---- PDE kernel: 2048 blocks * 4 waves; block-task BT block-uniform. ----
__global__ __launch_bounds__(256, 8) void sig_pde6(
    const float* __restrict__ X, const float* __restrict__ Y,
    float* __restrict__ out)
{
    __shared__ float red[4];
    const int wid  = threadIdx.x >> 6;
    const int lane = threadIdx.x & 63;

    float acc = 0.0f;
    const int nt = (blockIdx.x < (NBT - NBLOCKS6)) ? 2 : 1;

#pragma unroll 1
    for (int it = 0; it < nt; ++it) {
        const int BT = it ? (int)(NBLOCKS6 + blockIdx.x) : (int)blockIdx.x;

        // block-uniform decode -> (gram g, a, b0); b = b0 + wave id
        int g, a, b0;
        if (BT < XY_BLOCKS) {                  // XY: dense 64x64
            g = 2; a = BT >> 4; b0 = (BT & 15) << 2;
        } else {                               // XX / YY upper triangles
            int t = BT - XY_BLOCKS; g = 0;
            if (t >= TRI_BLOCKS) { t -= TRI_BLOCKS; g = 1; }
            int aa = 0;
            for (;;) { int nb = (67 - aa) >> 2; if (t < nb) break; t -= nb; ++aa; }
            a = aa; b0 = aa + (t << 2);
        }
        const int b = b0 + wid;

        if (g == 2 || b <= 63) {               // dead triangle waves skip
            // row paths: XX -> X, YY -> Y, XY -> X rows vs Y cols
            const float* A = (g == 1) ? Y : X;     // raw row path
            const float* Bp = (g == 0) ? X : Y;    // raw col path
            const float weight = (g == 2) ? (-2.0f / 4096.0f)
                                          : ((a == b ? 1.0f : 2.0f) / 4096.0f);

            // per-lane dY increments for cols j0=2l, j1=2l+1 from RAW rows
            // (lane 63's j1 chain is masked via c1=0; yb there is 0)
            float ya[16], yb_[16];
            {
                const float* Qb = Bp + b * 2048;          // raw pitch 128*16
                const int j0 = lane << 1;
                const int r2 = (j0 + 2 < 128) ? j0 + 2 : 127;
                const float4* R0 = (const float4*)(Qb + j0 * 16);
                const float4* R1 = (const float4*)(Qb + (j0 + 1) * 16);
                const float4* R2 = (const float4*)(Qb + r2 * 16);
#pragma unroll
                for (int q = 0; q < 4; ++q) {
                    float4 v0 = R0[q], v1 = R1[q], v2 = R2[q];
                    ya[4*q+0] = v1.x - v0.x;  yb_[4*q+0] = v2.x - v1.x;
                    ya[4*q+1] = v1.y - v0.y;  yb_[4*q+1] = v2.y - v1.y;
                    ya[4*q+2] = v1.z - v0.z;  yb_[4*q+2] = v2.z - v1.z;
                    ya[4*q+3] = v1.w - v0.w;  yb_[4*q+3] = v2.w - v1.w;
                }
            }
            // Pin fragments into VGPRs (opaque: cannot be rematerialized /
            // re-sunk into the row loop — round-2 reload bug).
#pragma unroll
            for (int d = 0; d < 16; ++d)
                asm volatile("" : "+v"(ya[d]), "+v"(yb_[d]));

            // block-uniform raw X rows -> s_load into SGPRs
            const int abase = __builtin_amdgcn_readfirstlane(a * 2048);
            const float4* Ar = (const float4*)(A + abase);

            float xc[16], xn[16];
            // prologue: row 0 -> E seeds (E = D(0) + 1); preload row 1
            float Es, Et;
            {
                float p0[16];
#pragma unroll
                for (int q = 0; q < 4; ++q) {
                    float4 v = Ar[q];
                    p0[4*q+0]=v.x; p0[4*q+1]=v.y; p0[4*q+2]=v.z; p0[4*q+3]=v.w;
                }
                float s0=0.f, s1=0.f, t0=0.f, t1=0.f;
#pragma unroll
                for (int d = 0; d < 16; d += 2) {
                    s0 = fmaf(p0[d],   ya[d],    s0);
                    s1 = fmaf(p0[d+1], ya[d+1],  s1);
                    t0 = fmaf(p0[d],   yb_[d],   t0);
                    t1 = fmaf(p0[d+1], yb_[d+1], t1);
                }
                Es = (s0 + s1) + 1.0f;
                Et = (t0 + t1) + 1.0f;
            }
#pragma unroll
            for (int q = 0; q < 4; ++q) {          // xc = raw row 1
                float4 v = Ar[4 + q];
                xc[4*q+0]=v.x; xc[4*q+1]=v.y; xc[4*q+2]=v.z; xc[4*q+3]=v.w;
            }

            float g_lo = 1.0f, g_hi = 1.0f;        // G[r][2l+1], G[r][2l+2]
            const bool last = (lane == 63);

            // row r uses raw row r+1: i = D(r+1) - (D(r)+1) = inc - 1
#define SIG_ROW(XROW)                                                       \
            {                                                               \
                float s0=0.f, s1=0.f, t0=0.f, t1=0.f;                       \
                _Pragma("unroll")                                           \
                for (int d = 0; d < 16; d += 2) {                           \
                    s0 = fmaf(XROW[d],   ya[d],    s0);                     \
                    s1 = fmaf(XROW[d+1], ya[d+1],  s1);                     \
                    t0 = fmaf(XROW[d],   yb_[d],   t0);                     \
                    t1 = fmaf(XROW[d+1], yb_[d+1], t1);                     \
                }                                                           \
                const float Ds = s0 + s1, Dt = t0 + t1;                     \
                const float i0 = Ds - Es;          /* inc(r, 2l)   - 1 */   \
                const float i1 = Dt - Et;          /* inc(r, 2l+1) - 1 */   \
                Es = Ds + 1.0f;  Et = Dt + 1.0f;                            \
                const float gl = wave_shr1(g_hi, 1.0f);  /* G[r][2l] */     \
                const float c0 = fmaf(gl, i0, g_lo);                        \
                const float c1 = last ? 0.0f : fmaf(g_lo, i1, g_hi);        \
                const float S  = wave_scan_incl(c0 + c1);                   \
                g_lo = (S - c1) + 1.0f;                                     \
                g_hi = S + 1.0f;                                            \
            }

            // ping-pong SGPR row buffers, depth-1 prefetch of raw rows
#pragma unroll 1
            for (int r = 0; r < 126; r += 2) {
#pragma unroll
                for (int q = 0; q < 4; ++q) {      // xn = raw row r+2
                    float4 v = Ar[4*(r+2)+q];
                    xn[4*q+0]=v.x; xn[4*q+1]=v.y; xn[4*q+2]=v.z; xn[4*q+3]=v.w;
                }
                SIG_ROW(xc)                        // row r (raw r+1)
#pragma unroll
                for (int q = 0; q < 4; ++q) {      // xc = raw row r+3
                    float4 v = Ar[4*(r+3)+q];
                    xc[4*q+0]=v.x; xc[4*q+1]=v.y; xc[4*q+2]=v.z; xc[4*q+3]=v.w;
                }
                SIG_ROW(xn)                        // row r+1 (raw r+2)
            }
            SIG_ROW(xc)                            // row 126 (raw row 127)
#undef SIG_ROW

            const float kab = __builtin_bit_cast(float,
                __builtin_amdgcn_readlane(__builtin_bit_cast(int, g_lo), 63));
            acc = fmaf(weight, kab, acc);
        }
    }

    // fused reduction: 4 waves -> LDS -> one atomic per block
    if (lane == 0) red[wid] = acc;
    __syncthreads();
    if (threadIdx.x == 0)
        atomicAdd(out, (red[0] + red[1]) + (red[2] + red[3]));
}

extern "C" void kernel_launch(void* const* d_in, const int* in_sizes, int n_in,
                              void* d_out, int out_size, void* d_ws, size_t ws_size,
                              hipStream_t stream) {
    const float* X = (const float*)d_in[0];
    const float* Y = (const float*)d_in[1];
    float* out = (float*)d_out;
    (void)d_ws; (void)ws_size;

    hipMemsetAsync(out, 0, sizeof(float), stream);
    sig_pde6<<<NBLOCKS6, 256, 0, stream>>>(X, Y, out);
}